// Round 6
// baseline (367.640 us; speedup 1.0000x reference)
//
#include <hip/hip_runtime.h>

// Performer (FAVOR+) encoder block, bf16 MFMA pipeline. Round 6:
//  - k_gemm256: T4 counted-vmcnt pipeline (vmcnt(8) in-loop, raw s_barrier,
//    refill-after-read-barrier), 2 K-tiles in flight, never drain-0 in loop
//  - attn-out residual reads xb (bf16) instead of x (f32)
// B=32 L=1024 HID=512 H=8 DH=64 FF=2048, N=32768 tokens.
//
// ws (~106.1 MiB):
//   [0,32M)   qp  -> hb after favor_num (hb updated in-place by FFN2)
//   [32M,64M) kp  -> attn after favor_kv -> ffa rows<16384 (low)
//   [64M,96M) vb  -> hpreB after favor   -> ffa rows<16384 (high)
//   [96M,..)  wqkvT, woT, w1T, w2T, kvt, ksum, bqkv
// d_out (64 MiB): xb bf16 [0,32M) + favor partials [32M,48.25M) early;
//   ffa rows>=16384 during FFN; final LN2 f32 output.

#define DI __device__ __forceinline__
#define AS1 __attribute__((address_space(1)))
#define AS3 __attribute__((address_space(3)))
#define GLD16(g, l) __builtin_amdgcn_global_load_lds((const AS1 void*)(g), (AS3 void*)(l), 16, 0, 0)

typedef __attribute__((ext_vector_type(8))) short bf16x8;
typedef __attribute__((ext_vector_type(4))) float f32x4;

DI float b2f(short s){ unsigned int u = ((unsigned int)(unsigned short)s) << 16; float f; __builtin_memcpy(&f, &u, 4); return f; }
DI short f2b(float f){ unsigned int u; __builtin_memcpy(&u, &f, 4); u += 0x7fffu + ((u >> 16) & 1u); return (short)(u >> 16); }

constexpr int Ll = 1024;
constexpr int SPLIT = 16384;   // row split between ws-resident and d_out-resident ffa

// ---------------- x -> bf16 ----------------
__global__ __launch_bounds__(256) void k_cvt_x(const float* __restrict__ x, short* __restrict__ xb){
  long i = (long)blockIdx.x * 256 + threadIdx.x;
  const float4* p = (const float4*)x + i * 2;
  float4 a = p[0], b = p[1];
  bf16x8 o;
  o[0]=f2b(a.x); o[1]=f2b(a.y); o[2]=f2b(a.z); o[3]=f2b(a.w);
  o[4]=f2b(b.x); o[5]=f2b(b.y); o[6]=f2b(b.z); o[7]=f2b(b.w);
  *((bf16x8*)xb + i) = o;
}

// ---------------- transpose + convert: in f32 [R][C] -> out bf16 [C][R] ----------------
__global__ void k_tcvt(const float* __restrict__ in, short* __restrict__ out, int R, int C){
  __shared__ float t[32][33];
  int c0 = blockIdx.x * 32, r0 = blockIdx.y * 32;
  int x = threadIdx.x, y = threadIdx.y;   // block (32,8)
  #pragma unroll
  for (int j = 0; j < 4; ++j) t[y + 8*j][x] = in[(long)(r0 + y + 8*j) * C + c0 + x];
  __syncthreads();
  #pragma unroll
  for (int j = 0; j < 4; ++j) out[(long)(c0 + y + 8*j) * R + r0 + x] = f2b(t[x][y + 8*j]);
}

// 4x [512,512] transposes in one launch (z picks matrix)
__global__ void k_tcvt4(const float* __restrict__ s0, const float* __restrict__ s1,
                        const float* __restrict__ s2, const float* __restrict__ s3,
                        short* __restrict__ d0, short* __restrict__ d1,
                        short* __restrict__ d2, short* __restrict__ d3){
  __shared__ float t[32][33];
  int z = blockIdx.z;
  const float* in = z == 0 ? s0 : z == 1 ? s1 : z == 2 ? s2 : s3;
  short* out      = z == 0 ? d0 : z == 1 ? d1 : z == 2 ? d2 : d3;
  int c0 = blockIdx.x * 32, r0 = blockIdx.y * 32;
  int x = threadIdx.x, y = threadIdx.y;
  #pragma unroll
  for (int j = 0; j < 4; ++j) t[y + 8*j][x] = in[(long)(r0 + y + 8*j) * 512 + c0 + x];
  __syncthreads();
  #pragma unroll
  for (int j = 0; j < 4; ++j) out[(long)(c0 + y + 8*j) * 512 + r0 + x] = f2b(t[x][y + 8*j]);
}

__global__ void k_pack_bias(const float* __restrict__ bq, const float* __restrict__ bk,
                            const float* __restrict__ bv, float* __restrict__ bqkv){
  int i = blockIdx.x * 256 + threadIdx.x;
  if (i < 512) bqkv[i] = bq[i];
  else if (i < 1024) bqkv[i] = bk[i - 512];
  else if (i < 1536) bqkv[i] = bv[i - 1024];
}

// ---------------- 256x256 bf16 MFMA GEMM, 8 waves, counted-vmcnt dbuf pipeline ----
// A [M,KD] bf16 row-major (A1 used for global rows >= SPLIT when A1 != A0).
// BT [NT*256,KD] bf16 row-major. Grid 1D, G = MT*NT (G%8==0), XCD swizzle.
// LDS (128 KiB): A[buf][half][128][64] | B[buf][half][128][64], 16B slot s of row r
// holds global chunk s^(r&7) (involution; conflict-free ds_read_b128).
// Pipeline: 2 K-tiles of global_load_lds in flight; per tile:
//   s_waitcnt vmcnt(8) [vmcnt(0) on last] -> s_barrier -> ds_read+MFMA ->
//   s_barrier -> refill this buffer for kt+2.  Never drain-0 in steady state.
// EPI: 0=QKV(phi->qp,kp,vb)  1=attn-out(+bo+xb(bf16) -> bf16 oQ)
//      2=FFN1(relu -> bf16 oQ/o1 row-split, stride 2048)  3=FFN2(+bias+oQ, in-place bf16 oQ)
template<int EPI, int KD>
__global__ __launch_bounds__(512, 2) void k_gemm256(
    const short* __restrict__ A0, const short* __restrict__ A1,
    const short* __restrict__ BT, int NT,
    const float* __restrict__ bias, const short* __restrict__ residX,
    short* __restrict__ oQ, short* __restrict__ oK, short* __restrict__ oV,
    short* __restrict__ o1)
{
  __shared__ short lds[65536];              // 128 KiB
  const int tid = threadIdx.x;
  const int w = tid >> 6, lane = tid & 63;
  const int wm = w >> 2, wn = w & 3;        // 2M x 4N wave grid; per-wave out 128x64
  const int lg = lane >> 4, lr = lane & 15;
  const int lrow = lane >> 3, lslot = (lane & 7) ^ lrow;

  const int per = gridDim.x >> 3;
  const int wg = (blockIdx.x & 7) * per + (blockIdx.x >> 3);
  const long m0 = (long)(wg / NT) * 256, n0 = (long)(wg % NT) * 256;

  const short* Ause = A0;
  long mbase = m0;
  if (A1 != A0 && m0 >= SPLIT) { Ause = A1; mbase = m0 - SPLIT; }

  f32x4 acc[8][4];
  #pragma unroll
  for (int i = 0; i < 8; ++i)
    #pragma unroll
    for (int j = 0; j < 4; ++j) acc[i][j] = 0.f;

  // 8 GLD16 per thread per K-tile (A: 2 half x 2 q; B: same)
  auto stage_all = [&](int buf, int k0){
    #pragma unroll
    for (int half = 0; half < 2; ++half)
      #pragma unroll
      for (int q = 0; q < 2; ++q) {
        int r = w * 16 + q * 8;
        GLD16(Ause + (mbase + half * 128 + r + lrow) * KD + k0 + lslot * 8,
              (char*)lds + (buf * 16384 + half * 8192 + r * 64) * 2);
        GLD16(BT + (n0 + half * 128 + r + lrow) * KD + k0 + lslot * 8,
              (char*)lds + (32768 + buf * 16384 + half * 8192 + r * 64) * 2);
      }
  };

  constexpr int NKT = KD / 64;
  stage_all(0, 0);
  stage_all(1, 64);                         // 16 loads/thread in flight

  for (int kt = 0; kt < NKT; ++kt) {
    const int cur = kt & 1;
    if (kt + 1 < NKT) { asm volatile("s_waitcnt vmcnt(8)" ::: "memory"); }
    else              { asm volatile("s_waitcnt vmcnt(0)" ::: "memory"); }
    __builtin_amdgcn_s_barrier();           // buf[cur] ready block-wide

    const char* Ab = (const char*)lds + (cur * 16384 + wm * 8192) * 2;
    const char* Bb = (const char*)lds + (32768 + cur * 16384 + (wn >> 1) * 8192) * 2;

    bf16x8 fB[2][2][2];                     // [qc][j][kk] held for whole K-tile
    #pragma unroll
    for (int qc = 0; qc < 2; ++qc)
      #pragma unroll
      for (int j = 0; j < 2; ++j)
        #pragma unroll
        for (int kk = 0; kk < 2; ++kk) {
          int rb = (wn & 1) * 64 + qc * 32 + j * 16 + lr;
          fB[qc][j][kk] = *(const bf16x8*)(Bb + rb * 128 + ((kk * 64 + lg * 16) ^ ((rb & 7) << 4)));
        }
    #pragma unroll
    for (int qr = 0; qr < 2; ++qr) {
      bf16x8 fA[4][2];
      #pragma unroll
      for (int i = 0; i < 4; ++i)
        #pragma unroll
        for (int kk = 0; kk < 2; ++kk) {
          int ra = qr * 64 + i * 16 + lr;
          fA[i][kk] = *(const bf16x8*)(Ab + ra * 128 + ((kk * 64 + lg * 16) ^ ((ra & 7) << 4)));
        }
      __builtin_amdgcn_s_setprio(1);
      #pragma unroll
      for (int i = 0; i < 4; ++i)
        #pragma unroll
        for (int qc = 0; qc < 2; ++qc)
          #pragma unroll
          for (int j = 0; j < 2; ++j)
            #pragma unroll
            for (int kk = 0; kk < 2; ++kk)
              acc[qr * 4 + i][qc * 2 + j] =
                __builtin_amdgcn_mfma_f32_16x16x32_bf16(fA[i][kk], fB[qc][j][kk], acc[qr * 4 + i][qc * 2 + j], 0, 0, 0);
      __builtin_amdgcn_s_setprio(0);
    }

    __builtin_amdgcn_s_barrier();           // all reads of buf[cur] retired block-wide
    if (kt + 2 < NKT) stage_all(cur, (kt + 2) * 64);   // refill AFTER read barrier
  }

  #pragma unroll
  for (int fr = 0; fr < 8; ++fr)
    #pragma unroll
    for (int fc = 0; fc < 4; ++fc)
      #pragma unroll
      for (int r = 0; r < 4; ++r) {
        int grow = (int)m0 + wm * 128 + fr * 16 + lg * 4 + r;  // C/D: row=(lane>>4)*4+reg
        int gcol = (int)n0 + wn * 64 + fc * 16 + lr;           //      col=lane&15
        float v = acc[fr][fc][r];
        if constexpr (EPI == 0) {
          v += bias[gcol];
          int which = gcol >> 9, hd = gcol & 511, h = hd >> 6, d = hd & 63;
          int b = grow >> 10, l = grow & 1023;
          long o = ((long)(b * 8 + h) * 1024 + l) * 64 + d;
          if (which == 2) oV[o] = f2b(v);
          else { float p = fmaxf(v, 0.f) + 1e-3f; if (which) oK[o] = f2b(p); else oQ[o] = f2b(p); }
        } else if constexpr (EPI == 1) {
          v += bias[gcol] + b2f(residX[(long)grow * 512 + gcol]);
          oQ[(long)grow * 512 + gcol] = f2b(v);
        } else if constexpr (EPI == 2) {
          v = fmaxf(v + bias[gcol], 0.f);
          if (grow < SPLIT) oQ[(long)grow * 2048 + gcol] = f2b(v);
          else              o1[(long)(grow - SPLIT) * 2048 + gcol] = f2b(v);
        } else {
          long idx = (long)grow * 512 + gcol;
          v += bias[gcol] + b2f(oQ[idx]);
          oQ[idx] = f2b(v);
        }
      }
}

// ---------------- FAVOR kv partials: chunk c sums l in [c*256, c*256+256) ----------------
__global__ __launch_bounds__(256) void k_fkv_part(const short* __restrict__ kp, const short* __restrict__ vb,
                                                  float* __restrict__ kvp, float* __restrict__ ksp)
{
  constexpr int LS = 72;
  __shared__ short kps[64 * LS];
  __shared__ short vps[64 * LS];
  int bh = blockIdx.x & 255, c = blockIdx.x >> 8;
  const short* kpp = kp + (long)bh * Ll * 64;
  const short* vpp = vb + (long)bh * Ll * 64;
  int tid = threadIdx.x;
  int mb = (tid & 15) * 4, db = (tid >> 4) * 4;
  float acc[4][4];
  float ks[4] = {0.f, 0.f, 0.f, 0.f};
  #pragma unroll
  for (int i = 0; i < 4; ++i)
    #pragma unroll
    for (int j = 0; j < 4; ++j) acc[i][j] = 0.f;

  for (int l0 = c * 256; l0 < c * 256 + 256; l0 += 64) {
    __syncthreads();
    #pragma unroll
    for (int s = 0; s < 2; ++s) {
      int idx = tid + s * 256;
      int row = idx >> 3, c8 = idx & 7;
      *(bf16x8*)(&kps[row * LS + c8 * 8]) = *(const bf16x8*)(kpp + (long)(l0 + row) * 64 + c8 * 8);
      *(bf16x8*)(&vps[row * LS + c8 * 8]) = *(const bf16x8*)(vpp + (long)(l0 + row) * 64 + c8 * 8);
    }
    __syncthreads();
    #pragma unroll 4
    for (int l = 0; l < 64; ++l) {
      short4 ka = *(const short4*)(&kps[l * LS + mb]);
      short4 va = *(const short4*)(&vps[l * LS + db]);
      float kf[4] = {b2f(ka.x), b2f(ka.y), b2f(ka.z), b2f(ka.w)};
      float vf[4] = {b2f(va.x), b2f(va.y), b2f(va.z), b2f(va.w)};
      if (tid < 16) { ks[0] += kf[0]; ks[1] += kf[1]; ks[2] += kf[2]; ks[3] += kf[3]; }
      #pragma unroll
      for (int i = 0; i < 4; ++i)
        #pragma unroll
        for (int j = 0; j < 4; ++j) acc[i][j] += kf[i] * vf[j];
    }
  }
  float* kout = kvp + (long)c * 1048576 + (long)bh * 4096;
  #pragma unroll
  for (int i = 0; i < 4; ++i)
    #pragma unroll
    for (int j = 0; j < 4; ++j)
      kout[(db + j) * 64 + mb + i] = acc[i][j];
  if (tid < 16) {
    #pragma unroll
    for (int i = 0; i < 4; ++i) ksp[(long)c * 16384 + bh * 64 + mb + i] = ks[i];
  }
}

__global__ __launch_bounds__(256) void k_fkv_reduce(const float* __restrict__ kvp, const float* __restrict__ ksp,
                                                    short* __restrict__ kvt, float* __restrict__ ksum)
{
  int g = blockIdx.x * 256 + threadIdx.x;
  float s = kvp[g] + kvp[g + 1048576] + kvp[g + 2 * 1048576] + kvp[g + 3 * 1048576];
  kvt[g] = f2b(s);
  if (g < 16384)
    ksum[g] = ksp[g] + ksp[g + 16384] + ksp[g + 2 * 16384] + ksp[g + 3 * 16384];
}

// ---------------- FAVOR: attn = (qp @ kv)/den ----------------
__global__ __launch_bounds__(256) void k_favor_num(const short* __restrict__ qp, const short* __restrict__ kvt,
                                                   const float* __restrict__ ksum, short* __restrict__ attn)
{
  constexpr int LS = 72;
  __shared__ short Qs[128 * 64];
  __shared__ short kvs[64 * LS];
  __shared__ float part[256];
  __shared__ float den[128];
  int bh = blockIdx.x >> 3, lt = blockIdx.x & 7;
  int b = bh >> 3, h = bh & 7;
  const short* qpp = qp + ((long)bh * Ll + lt * 128) * 64;
  int tid = threadIdx.x;
  int wave = tid >> 6, lane = tid & 63;
  int lrow = lane >> 3, lslot = (lane & 7) ^ lrow;

  #pragma unroll
  for (int s = 0; s < 4; ++s) {
    int rs = (s * 4 + wave) * 8;
    GLD16(qpp + (long)(rs + lrow) * 64 + lslot * 8, &Qs[rs * 64]);
  }
  #pragma unroll
  for (int s = 0; s < 2; ++s) {
    int idx = tid + s * 256;
    int row = idx >> 3, c8 = idx & 7;
    *(bf16x8*)(&kvs[row * LS + c8 * 8]) = *(const bf16x8*)(kvt + (long)bh * 4096 + row * 64 + c8 * 8);
  }
  __syncthreads();
  {
    int r = tid >> 1, half = tid & 1;
    const float* kss = ksum + bh * 64 + half * 32;
    float s = 0.f;
    #pragma unroll
    for (int c = 0; c < 4; ++c) {
      int cc = half * 4 + c;
      bf16x8 v = *(const bf16x8*)((const char*)Qs + r * 128 + ((cc * 16) ^ ((r & 7) << 4)));
      #pragma unroll
      for (int j = 0; j < 8; ++j) s += b2f(v[j]) * kss[c * 8 + j];
    }
    part[tid] = s;
  }
  __syncthreads();
  if (tid < 128) den[tid] = part[2 * tid] + part[2 * tid + 1];
  __syncthreads();

  int wr = wave >> 1, wc = wave & 1;
  int lg = lane >> 4, lr = lane & 15;
  f32x4 acc[4][2];
  #pragma unroll
  for (int i = 0; i < 4; ++i) { acc[i][0] = 0.f; acc[i][1] = 0.f; }
  #pragma unroll
  for (int kk = 0; kk < 2; ++kk) {
    bf16x8 af[4], bfr[2];
    #pragma unroll
    for (int i = 0; i < 4; ++i) {
      int ra = wr * 64 + i * 16 + lr;
      af[i] = *(const bf16x8*)((const char*)Qs + ra * 128 + ((kk * 64 + lg * 16) ^ ((ra & 7) << 4)));
    }
    #pragma unroll
    for (int j = 0; j < 2; ++j)
      bfr[j] = *(const bf16x8*)(&kvs[(wc * 32 + j * 16 + lr) * LS + kk * 32 + lg * 8]);
    #pragma unroll
    for (int i = 0; i < 4; ++i)
      #pragma unroll
      for (int j = 0; j < 2; ++j)
        acc[i][j] = __builtin_amdgcn_mfma_f32_16x16x32_bf16(af[i], bfr[j], acc[i][j], 0, 0, 0);
  }
  #pragma unroll
  for (int i = 0; i < 4; ++i)
    #pragma unroll
    for (int j = 0; j < 2; ++j)
      #pragma unroll
      for (int r = 0; r < 4; ++r) {
        int rl = wr * 64 + i * 16 + lg * 4 + r;
        int d  = wc * 32 + j * 16 + lr;
        int t  = b * Ll + lt * 128 + rl;
        attn[(long)t * 512 + h * 64 + d] = f2b(acc[i][j][r] / den[rl]);
      }
}

// ---------------- LayerNorm, bf16 in -> bf16 out (one wave per row of 512) ----------------
__global__ __launch_bounds__(256) void k_ln_bb(const short* __restrict__ in, const float* __restrict__ sc,
                                               const float* __restrict__ bi, short* __restrict__ ob)
{
  int row = blockIdx.x * 4 + (threadIdx.x >> 6);
  int lane = threadIdx.x & 63;
  bf16x8 v = *((const bf16x8*)(in + (long)row * 512) + lane);
  float e[8];
  #pragma unroll
  for (int j = 0; j < 8; ++j) e[j] = b2f(v[j]);
  float s = 0.f, s2 = 0.f;
  #pragma unroll
  for (int j = 0; j < 8; ++j) { s += e[j]; s2 += e[j] * e[j]; }
  #pragma unroll
  for (int off = 32; off; off >>= 1) { s += __shfl_xor(s, off); s2 += __shfl_xor(s2, off); }
  float mu = s * (1.f / 512.f);
  float var = s2 * (1.f / 512.f) - mu * mu;
  float rstd = rsqrtf(var + 1e-6f);
  int c0 = lane * 8;
  bf16x8 o;
  #pragma unroll
  for (int j = 0; j < 8; ++j) o[j] = f2b((e[j] - mu) * rstd * sc[c0 + j] + bi[c0 + j]);
  *((bf16x8*)(ob + (long)row * 512) + lane) = o;
}

// ---------------- LayerNorm, bf16 in -> f32 out ----------------
__global__ __launch_bounds__(256) void k_ln_bf(const short* __restrict__ in, const float* __restrict__ sc,
                                               const float* __restrict__ bi, float* __restrict__ of)
{
  int row = blockIdx.x * 4 + (threadIdx.x >> 6);
  int lane = threadIdx.x & 63;
  bf16x8 v = *((const bf16x8*)(in + (long)row * 512) + lane);
  float e[8];
  #pragma unroll
  for (int j = 0; j < 8; ++j) e[j] = b2f(v[j]);
  float s = 0.f, s2 = 0.f;
  #pragma unroll
  for (int j = 0; j < 8; ++j) { s += e[j]; s2 += e[j] * e[j]; }
  #pragma unroll
  for (int off = 32; off; off >>= 1) { s += __shfl_xor(s, off); s2 += __shfl_xor(s2, off); }
  float mu = s * (1.f / 512.f);
  float var = s2 * (1.f / 512.f) - mu * mu;
  float rstd = rsqrtf(var + 1e-6f);
  int c0 = lane * 8;
  float o0[4], o1[4];
  #pragma unroll
  for (int j = 0; j < 4; ++j) {
    o0[j] = (e[j]     - mu) * rstd * sc[c0 + j]     + bi[c0 + j];
    o1[j] = (e[4 + j] - mu) * rstd * sc[c0 + 4 + j] + bi[c0 + 4 + j];
  }
  *(float4*)(of + (long)row * 512 + c0)     = (float4){o0[0], o0[1], o0[2], o0[3]};
  *(float4*)(of + (long)row * 512 + c0 + 4) = (float4){o1[0], o1[1], o1[2], o1[3]};
}

extern "C" void kernel_launch(void* const* d_in, const int* in_sizes, int n_in,
                              void* d_out, int out_size, void* d_ws, size_t ws_size,
                              hipStream_t stream)
{
  const float* x   = (const float*)d_in[0];
  const float* Wq  = (const float*)d_in[1];
  const float* bq  = (const float*)d_in[2];
  const float* Wk  = (const float*)d_in[3];
  const float* bk  = (const float*)d_in[4];
  const float* Wv  = (const float*)d_in[5];
  const float* bv  = (const float*)d_in[6];
  const float* Wo  = (const float*)d_in[7];
  const float* bo  = (const float*)d_in[8];
  const float* g1  = (const float*)d_in[9];
  const float* be1 = (const float*)d_in[10];
  const float* W1  = (const float*)d_in[11];
  const float* b1  = (const float*)d_in[12];
  const float* W2  = (const float*)d_in[13];
  const float* b2  = (const float*)d_in[14];
  const float* g2  = (const float*)d_in[15];
  const float* be2 = (const float*)d_in[16];
  float* out = (float*)d_out;

  const long MB = 1024L * 1024L;
  char* ws = (char*)d_ws;
  short* qp    = (short*)(ws + 0 * MB);     // 32 MiB; later hb (FFN2 updates in place)
  short* kp    = (short*)(ws + 32 * MB);    // 32 MiB; later attn, then ffa0 (low)
  short* vb    = (short*)(ws + 64 * MB);    // 32 MiB; later hpreB, then ffa0 (high)
  short* attn  = (short*)(ws + 32 * MB);
  short* hb    = (short*)(ws + 0 * MB);
  short* hpreB = (short*)(ws + 64 * MB);
  short* ffa0  = (short*)(ws + 32 * MB);    // 64 MiB: rows [0,16384) x 2048 bf16
  short* wqkvT = (short*)(ws + 96 * MB);    // 1.5 MiB [1536,512]
  short* woT   = (short*)(ws + 98 * MB);    // 0.5 MiB [512,512]
  short* w1T   = (short*)(ws + 99 * MB);    // 2 MiB   [2048,512]
  short* w2T   = (short*)(ws + 101 * MB);   // 2 MiB   [512,2048]
  short* kvt   = (short*)(ws + 103 * MB);   // 2 MiB   [BH,64,64]
  float* ksum  = (float*)(ws + 105 * MB);   // 64 KiB
  float* bqkv  = (float*)(ws + 105 * MB + 65536);

  // d_out scratch: xb [0,32M), favor partials [32M,48.25M), later ffa1 [0,64M)
  short* xb   = (short*)d_out;
  float* kvp  = (float*)((char*)d_out + 32 * MB);
  float* ksp  = (float*)((char*)d_out + 48 * MB);
  short* ffa1 = (short*)d_out;              // rows [16384,32768) x 2048 bf16

  dim3 tb(32, 8);
  k_cvt_x<<<8192, 256, 0, stream>>>(x, xb);
  k_tcvt4<<<dim3(16, 16, 4), tb, 0, stream>>>(Wq, Wk, Wv, Wo,
      wqkvT, wqkvT + 512 * 512, wqkvT + 1024 * 512, woT);
  k_tcvt<<<dim3(64, 16), tb, 0, stream>>>(W1, w1T, 512, 2048);
  k_tcvt<<<dim3(16, 64), tb, 0, stream>>>(W2, w2T, 2048, 512);
  k_pack_bias<<<6, 256, 0, stream>>>(bq, bk, bv, bqkv);

  // QKV projection: 128 m-tiles x 6 n-tiles = 768 blocks
  k_gemm256<0, 512><<<768, 512, 0, stream>>>(xb, xb, wqkvT, 6, bqkv, nullptr, qp, kp, vb, nullptr);
  k_fkv_part<<<1024, 256, 0, stream>>>(kp, vb, kvp, ksp);
  k_fkv_reduce<<<4096, 256, 0, stream>>>(kvp, ksp, kvt, ksum);
  k_favor_num<<<2048, 256, 0, stream>>>(qp, kvt, ksum, attn);
  // attn-out + bo + xb(bf16 resid) -> bf16 hpreB: 128 x 2 = 256 blocks
  k_gemm256<1, 512><<<256, 512, 0, stream>>>(attn, attn, woT, 2, bo, xb, hpreB, nullptr, nullptr, nullptr);
  k_ln_bb<<<8192, 256, 0, stream>>>(hpreB, g1, be1, hb);
  // FFN1: 128 x 8 = 1024 blocks, output row-split ffa0/ffa1
  k_gemm256<2, 512><<<1024, 512, 0, stream>>>(hb, hb, w1T, 8, b1, nullptr, ffa0, nullptr, nullptr, ffa1);
  // FFN2: 128 x 2 = 256 blocks, A row-split, residual in-place into hb
  k_gemm256<3, 2048><<<256, 512, 0, stream>>>(ffa0, ffa1, w2T, 2, b2, nullptr, hb, nullptr, nullptr, nullptr);
  k_ln_bf<<<8192, 256, 0, stream>>>(hb, g2, be2, out);
}

// Round 7
// 365.801 us; speedup vs baseline: 1.0050x; 1.0050x over previous
//
#include <hip/hip_runtime.h>

// Performer (FAVOR+) encoder block, bf16 MFMA pipeline. Round 7:
//  - k_gemm256: full 8-phase schedule (T3+T4+T5): per 2 K-tiles, 8 phases of
//    {ds_read quad | stage 1 half-tile | barrier | 16 MFMA | barrier},
//    counted vmcnt(4) gates at phases 4/8 only. Same math order as round 5.
//  - everything else identical to round 5/6.
// B=32 L=1024 HID=512 H=8 DH=64 FF=2048, N=32768 tokens.

#define DI __device__ __forceinline__
#define AS1 __attribute__((address_space(1)))
#define AS3 __attribute__((address_space(3)))
#define GLD16(g, l) __builtin_amdgcn_global_load_lds((const AS1 void*)(g), (AS3 void*)(l), 16, 0, 0)

typedef __attribute__((ext_vector_type(8))) short bf16x8;
typedef __attribute__((ext_vector_type(4))) float f32x4;

DI float b2f(short s){ unsigned int u = ((unsigned int)(unsigned short)s) << 16; float f; __builtin_memcpy(&f, &u, 4); return f; }
DI short f2b(float f){ unsigned int u; __builtin_memcpy(&u, &f, 4); u += 0x7fffu + ((u >> 16) & 1u); return (short)(u >> 16); }

constexpr int Ll = 1024;
constexpr int SPLIT = 16384;

// ---------------- x -> bf16 ----------------
__global__ __launch_bounds__(256) void k_cvt_x(const float* __restrict__ x, short* __restrict__ xb){
  long i = (long)blockIdx.x * 256 + threadIdx.x;
  const float4* p = (const float4*)x + i * 2;
  float4 a = p[0], b = p[1];
  bf16x8 o;
  o[0]=f2b(a.x); o[1]=f2b(a.y); o[2]=f2b(a.z); o[3]=f2b(a.w);
  o[4]=f2b(b.x); o[5]=f2b(b.y); o[6]=f2b(b.z); o[7]=f2b(b.w);
  *((bf16x8*)xb + i) = o;
}

// ---------------- transpose + convert: in f32 [R][C] -> out bf16 [C][R] ----------------
__global__ void k_tcvt(const float* __restrict__ in, short* __restrict__ out, int R, int C){
  __shared__ float t[32][33];
  int c0 = blockIdx.x * 32, r0 = blockIdx.y * 32;
  int x = threadIdx.x, y = threadIdx.y;
  #pragma unroll
  for (int j = 0; j < 4; ++j) t[y + 8*j][x] = in[(long)(r0 + y + 8*j) * C + c0 + x];
  __syncthreads();
  #pragma unroll
  for (int j = 0; j < 4; ++j) out[(long)(c0 + y + 8*j) * R + r0 + x] = f2b(t[x][y + 8*j]);
}

__global__ void k_tcvt4(const float* __restrict__ s0, const float* __restrict__ s1,
                        const float* __restrict__ s2, const float* __restrict__ s3,
                        short* __restrict__ d0, short* __restrict__ d1,
                        short* __restrict__ d2, short* __restrict__ d3){
  __shared__ float t[32][33];
  int z = blockIdx.z;
  const float* in = z == 0 ? s0 : z == 1 ? s1 : z == 2 ? s2 : s3;
  short* out      = z == 0 ? d0 : z == 1 ? d1 : z == 2 ? d2 : d3;
  int c0 = blockIdx.x * 32, r0 = blockIdx.y * 32;
  int x = threadIdx.x, y = threadIdx.y;
  #pragma unroll
  for (int j = 0; j < 4; ++j) t[y + 8*j][x] = in[(long)(r0 + y + 8*j) * 512 + c0 + x];
  __syncthreads();
  #pragma unroll
  for (int j = 0; j < 4; ++j) out[(long)(c0 + y + 8*j) * 512 + r0 + x] = f2b(t[x][y + 8*j]);
}

__global__ void k_pack_bias(const float* __restrict__ bq, const float* __restrict__ bk,
                            const float* __restrict__ bv, float* __restrict__ bqkv){
  int i = blockIdx.x * 256 + threadIdx.x;
  if (i < 512) bqkv[i] = bq[i];
  else if (i < 1024) bqkv[i] = bk[i - 512];
  else if (i < 1536) bqkv[i] = bv[i - 1024];
}

// ---------------- 256x256 bf16 MFMA GEMM, 8 waves, 8-phase schedule ----------------
// LDS (128 KiB): A[buf][half][128][64] | B[buf][half][128][64]; 16B slot s of row r
// holds global chunk s^(r&7).  Wave (wm,wn): out 128x64 at (wm*128, wn*64); reads
// A[buf][wm], B[buf][wn>>1] rows (wn&1)*64+..
// Per iteration (K-tiles t0=2it buf0, t1 buf1), 8 phases; stage map:
//  p1:A1lo<-t1  p2:A1hi<-t1  p3:B0lo<-t0+2  p4:B0hi<-t0+2 +vmcnt(4)
//  p5:A0lo<-t0+2 p6:A0hi<-t0+2 p7:B1lo<-t1+2 p8:B1hi<-t1+2 +vmcnt(4)
// Every region: >=1 barrier between last read retire and restage; reads gated by
// the phase-4/8 vmcnt. MFMA order identical to round 5 (same numerics).
template<int EPI, int KD>
__global__ __launch_bounds__(512, 2) void k_gemm256(
    const short* __restrict__ A0, const short* __restrict__ A1,
    const short* __restrict__ BT, int NT,
    const float* __restrict__ bias, const short* __restrict__ residX,
    short* __restrict__ oQ, short* __restrict__ oK, short* __restrict__ oV,
    short* __restrict__ o1)
{
  __shared__ short lds[65536];
  const int tid = threadIdx.x;
  const int w = tid >> 6, lane = tid & 63;
  const int wm = w >> 2, wn = w & 3;
  const int lg = lane >> 4, lr = lane & 15;
  const int lrow = lane >> 3, lslot = (lane & 7) ^ lrow;

  const int per = gridDim.x >> 3;
  const int wg = (blockIdx.x & 7) * per + (blockIdx.x >> 3);
  const long m0 = (long)(wg / NT) * 256, n0 = (long)(wg % NT) * 256;

  const short* Ause = A0;
  long mbase = m0;
  if (A1 != A0 && m0 >= SPLIT) { Ause = A1; mbase = m0 - SPLIT; }

  f32x4 acc[8][4];
  #pragma unroll
  for (int i = 0; i < 8; ++i)
    #pragma unroll
    for (int j = 0; j < 4; ++j) acc[i][j] = 0.f;

  const char* Abase = (const char*)lds + wm * 16384;            // half=wm, byte offset
  const char* Bbase = (const char*)lds + 65536 + (wn >> 1) * 16384;

#define STAGE_A(buf, half, t) do {                                              \
    int k0_ = (t) * 64;                                                         \
    _Pragma("unroll")                                                           \
    for (int q_ = 0; q_ < 2; ++q_) {                                            \
      int rs_ = w * 16 + q_ * 8;                                                \
      GLD16(Ause + (mbase + (half) * 128 + rs_ + lrow) * KD + k0_ + lslot * 8,  \
            (char*)lds + ((buf) * 16384 + (half) * 8192 + rs_ * 64) * 2);       \
    } } while (0)
#define STAGE_B(buf, half, t) do {                                              \
    int k0_ = (t) * 64;                                                         \
    _Pragma("unroll")                                                           \
    for (int q_ = 0; q_ < 2; ++q_) {                                            \
      int rs_ = w * 16 + q_ * 8;                                                \
      GLD16(BT + (n0 + (half) * 128 + rs_ + lrow) * KD + k0_ + lslot * 8,       \
            (char*)lds + (32768 + (buf) * 16384 + (half) * 8192 + rs_ * 64) * 2); \
    } } while (0)
#define READ_A(buf, qr) do {                                                    \
    _Pragma("unroll")                                                           \
    for (int i_ = 0; i_ < 4; ++i_)                                              \
      _Pragma("unroll")                                                         \
      for (int kk_ = 0; kk_ < 2; ++kk_) {                                       \
        int ra_ = (qr) * 64 + i_ * 16 + lr;                                     \
        fA[i_][kk_] = *(const bf16x8*)(Abase + (buf) * 32768 + ra_ * 128 +      \
                       ((kk_ * 64 + lg * 16) ^ ((ra_ & 7) << 4)));              \
      } } while (0)
#define READ_B(FB, buf, qc) do {                                                \
    _Pragma("unroll")                                                           \
    for (int j_ = 0; j_ < 2; ++j_)                                              \
      _Pragma("unroll")                                                         \
      for (int kk_ = 0; kk_ < 2; ++kk_) {                                       \
        int rb_ = (wn & 1) * 64 + (qc) * 32 + j_ * 16 + lr;                     \
        FB[j_][kk_] = *(const bf16x8*)(Bbase + (buf) * 32768 + rb_ * 128 +      \
                       ((kk_ * 64 + lg * 16) ^ ((rb_ & 7) << 4)));              \
      } } while (0)
#define MFMA_Q(qr, qc, FB) do {                                                 \
    __builtin_amdgcn_s_setprio(1);                                              \
    _Pragma("unroll")                                                           \
    for (int i_ = 0; i_ < 4; ++i_)                                              \
      _Pragma("unroll")                                                         \
      for (int j_ = 0; j_ < 2; ++j_)                                            \
        _Pragma("unroll")                                                       \
        for (int kk_ = 0; kk_ < 2; ++kk_)                                       \
          acc[(qr)*4+i_][(qc)*2+j_] = __builtin_amdgcn_mfma_f32_16x16x32_bf16(  \
              fA[i_][kk_], FB[j_][kk_], acc[(qr)*4+i_][(qc)*2+j_], 0, 0, 0);    \
    __builtin_amdgcn_s_setprio(0);                                              \
  } while (0)
#define BARR __builtin_amdgcn_s_barrier()
#define GATEC asm volatile("s_waitcnt vmcnt(4)" ::: "memory")
#define GATE0 asm volatile("s_waitcnt vmcnt(0)" ::: "memory")

  constexpr int NKT = KD / 64;
  bf16x8 fA[4][2], fB0[2][2], fB1[2][2];

  // prologue: K-tile 0 fully, K-tile 1 B-halves (A1 staged at p1/p2 of iter 0)
  STAGE_A(0, 0, 0); STAGE_A(0, 1, 0); STAGE_B(0, 0, 0); STAGE_B(0, 1, 0);
  STAGE_B(1, 0, 1); STAGE_B(1, 1, 1);
  GATEC; BARR;                       // K0's 8 loads landed; K1-B's 4 in flight

  for (int it = 0; it < NKT / 2; ++it) {
    const int t0 = 2 * it, t1 = 2 * it + 1;
    const bool s0 = (t0 + 2 < NKT), s1 = (t1 + 2 < NKT);
    // p1: A0-q0, B0-q0 | stage A1lo(t1)
    READ_A(0, 0); READ_B(fB0, 0, 0); STAGE_A(1, 0, t1);
    BARR; MFMA_Q(0, 0, fB0); BARR;
    // p2: B0-q1 | stage A1hi(t1)
    READ_B(fB1, 0, 1); STAGE_A(1, 1, t1);
    BARR; MFMA_Q(0, 1, fB1); BARR;
    // p3: A0-q1 | stage B0lo(t0+2)
    READ_A(0, 1); if (s0) STAGE_B(0, 0, t0 + 2);
    BARR; MFMA_Q(1, 0, fB0); BARR;
    // p4: stage B0hi(t0+2) | gate buf1
    if (s0) { STAGE_B(0, 1, t0 + 2); GATEC; } else { GATE0; }
    BARR; MFMA_Q(1, 1, fB1); BARR;
    // p5: A1-q0, B1-q0 | stage A0lo(t0+2)
    READ_A(1, 0); READ_B(fB0, 1, 0); if (s0) STAGE_A(0, 0, t0 + 2);
    BARR; MFMA_Q(0, 0, fB0); BARR;
    // p6: B1-q1 | stage A0hi(t0+2)
    READ_B(fB1, 1, 1); if (s0) STAGE_A(0, 1, t0 + 2);
    BARR; MFMA_Q(0, 1, fB1); BARR;
    // p7: A1-q1 | stage B1lo(t1+2)
    READ_A(1, 1); if (s1) STAGE_B(1, 0, t1 + 2);
    BARR; MFMA_Q(1, 0, fB0); BARR;
    // p8: stage B1hi(t1+2) | gate buf0'
    if (s1) { STAGE_B(1, 1, t1 + 2); GATEC; } else { GATE0; }
    BARR; MFMA_Q(1, 1, fB1); BARR;
  }

#undef STAGE_A
#undef STAGE_B
#undef READ_A
#undef READ_B
#undef MFMA_Q
#undef BARR
#undef GATEC
#undef GATE0

  #pragma unroll
  for (int fr = 0; fr < 8; ++fr)
    #pragma unroll
    for (int fc = 0; fc < 4; ++fc)
      #pragma unroll
      for (int r = 0; r < 4; ++r) {
        int grow = (int)m0 + wm * 128 + fr * 16 + lg * 4 + r;  // C/D: row=(lane>>4)*4+reg
        int gcol = (int)n0 + wn * 64 + fc * 16 + lr;           //      col=lane&15
        float v = acc[fr][fc][r];
        if constexpr (EPI == 0) {
          v += bias[gcol];
          int which = gcol >> 9, hd = gcol & 511, h = hd >> 6, d = hd & 63;
          int b = grow >> 10, l = grow & 1023;
          long o = ((long)(b * 8 + h) * 1024 + l) * 64 + d;
          if (which == 2) oV[o] = f2b(v);
          else { float p = fmaxf(v, 0.f) + 1e-3f; if (which) oK[o] = f2b(p); else oQ[o] = f2b(p); }
        } else if constexpr (EPI == 1) {
          v += bias[gcol] + b2f(residX[(long)grow * 512 + gcol]);
          oQ[(long)grow * 512 + gcol] = f2b(v);
        } else if constexpr (EPI == 2) {
          v = fmaxf(v + bias[gcol], 0.f);
          if (grow < SPLIT) oQ[(long)grow * 2048 + gcol] = f2b(v);
          else              o1[(long)(grow - SPLIT) * 2048 + gcol] = f2b(v);
        } else {
          long idx = (long)grow * 512 + gcol;
          v += bias[gcol] + b2f(oQ[idx]);
          oQ[idx] = f2b(v);
        }
      }
}

// ---------------- FAVOR kv partials: chunk c sums l in [c*256, c*256+256) ----------------
__global__ __launch_bounds__(256) void k_fkv_part(const short* __restrict__ kp, const short* __restrict__ vb,
                                                  float* __restrict__ kvp, float* __restrict__ ksp)
{
  constexpr int LS = 72;
  __shared__ short kps[64 * LS];
  __shared__ short vps[64 * LS];
  int bh = blockIdx.x & 255, c = blockIdx.x >> 8;
  const short* kpp = kp + (long)bh * Ll * 64;
  const short* vpp = vb + (long)bh * Ll * 64;
  int tid = threadIdx.x;
  int mb = (tid & 15) * 4, db = (tid >> 4) * 4;
  float acc[4][4];
  float ks[4] = {0.f, 0.f, 0.f, 0.f};
  #pragma unroll
  for (int i = 0; i < 4; ++i)
    #pragma unroll
    for (int j = 0; j < 4; ++j) acc[i][j] = 0.f;

  for (int l0 = c * 256; l0 < c * 256 + 256; l0 += 64) {
    __syncthreads();
    #pragma unroll
    for (int s = 0; s < 2; ++s) {
      int idx = tid + s * 256;
      int row = idx >> 3, c8 = idx & 7;
      *(bf16x8*)(&kps[row * LS + c8 * 8]) = *(const bf16x8*)(kpp + (long)(l0 + row) * 64 + c8 * 8);
      *(bf16x8*)(&vps[row * LS + c8 * 8]) = *(const bf16x8*)(vpp + (long)(l0 + row) * 64 + c8 * 8);
    }
    __syncthreads();
    #pragma unroll 4
    for (int l = 0; l < 64; ++l) {
      short4 ka = *(const short4*)(&kps[l * LS + mb]);
      short4 va = *(const short4*)(&vps[l * LS + db]);
      float kf[4] = {b2f(ka.x), b2f(ka.y), b2f(ka.z), b2f(ka.w)};
      float vf[4] = {b2f(va.x), b2f(va.y), b2f(va.z), b2f(va.w)};
      if (tid < 16) { ks[0] += kf[0]; ks[1] += kf[1]; ks[2] += kf[2]; ks[3] += kf[3]; }
      #pragma unroll
      for (int i = 0; i < 4; ++i)
        #pragma unroll
        for (int j = 0; j < 4; ++j) acc[i][j] += kf[i] * vf[j];
    }
  }
  float* kout = kvp + (long)c * 1048576 + (long)bh * 4096;
  #pragma unroll
  for (int i = 0; i < 4; ++i)
    #pragma unroll
    for (int j = 0; j < 4; ++j)
      kout[(db + j) * 64 + mb + i] = acc[i][j];
  if (tid < 16) {
    #pragma unroll
    for (int i = 0; i < 4; ++i) ksp[(long)c * 16384 + bh * 64 + mb + i] = ks[i];
  }
}

__global__ __launch_bounds__(256) void k_fkv_reduce(const float* __restrict__ kvp, const float* __restrict__ ksp,
                                                    short* __restrict__ kvt, float* __restrict__ ksum)
{
  int g = blockIdx.x * 256 + threadIdx.x;
  float s = kvp[g] + kvp[g + 1048576] + kvp[g + 2 * 1048576] + kvp[g + 3 * 1048576];
  kvt[g] = f2b(s);
  if (g < 16384)
    ksum[g] = ksp[g] + ksp[g + 16384] + ksp[g + 2 * 16384] + ksp[g + 3 * 16384];
}

// ---------------- FAVOR: attn = (qp @ kv)/den ----------------
__global__ __launch_bounds__(256) void k_favor_num(const short* __restrict__ qp, const short* __restrict__ kvt,
                                                   const float* __restrict__ ksum, short* __restrict__ attn)
{
  constexpr int LS = 72;
  __shared__ short Qs[128 * 64];
  __shared__ short kvs[64 * LS];
  __shared__ float part[256];
  __shared__ float den[128];
  int bh = blockIdx.x >> 3, lt = blockIdx.x & 7;
  int b = bh >> 3, h = bh & 7;
  const short* qpp = qp + ((long)bh * Ll + lt * 128) * 64;
  int tid = threadIdx.x;
  int wave = tid >> 6, lane = tid & 63;
  int lrow = lane >> 3, lslot = (lane & 7) ^ lrow;

  #pragma unroll
  for (int s = 0; s < 4; ++s) {
    int rs = (s * 4 + wave) * 8;
    GLD16(qpp + (long)(rs + lrow) * 64 + lslot * 8, &Qs[rs * 64]);
  }
  #pragma unroll
  for (int s = 0; s < 2; ++s) {
    int idx = tid + s * 256;
    int row = idx >> 3, c8 = idx & 7;
    *(bf16x8*)(&kvs[row * LS + c8 * 8]) = *(const bf16x8*)(kvt + (long)bh * 4096 + row * 64 + c8 * 8);
  }
  __syncthreads();
  {
    int r = tid >> 1, half = tid & 1;
    const float* kss = ksum + bh * 64 + half * 32;
    float s = 0.f;
    #pragma unroll
    for (int c = 0; c < 4; ++c) {
      int cc = half * 4 + c;
      bf16x8 v = *(const bf16x8*)((const char*)Qs + r * 128 + ((cc * 16) ^ ((r & 7) << 4)));
      #pragma unroll
      for (int j = 0; j < 8; ++j) s += b2f(v[j]) * kss[c * 8 + j];
    }
    part[tid] = s;
  }
  __syncthreads();
  if (tid < 128) den[tid] = part[2 * tid] + part[2 * tid + 1];
  __syncthreads();

  int wr = wave >> 1, wc = wave & 1;
  int lg = lane >> 4, lr = lane & 15;
  f32x4 acc[4][2];
  #pragma unroll
  for (int i = 0; i < 4; ++i) { acc[i][0] = 0.f; acc[i][1] = 0.f; }
  #pragma unroll
  for (int kk = 0; kk < 2; ++kk) {
    bf16x8 af[4], bfr[2];
    #pragma unroll
    for (int i = 0; i < 4; ++i) {
      int ra = wr * 64 + i * 16 + lr;
      af[i] = *(const bf16x8*)((const char*)Qs + ra * 128 + ((kk * 64 + lg * 16) ^ ((ra & 7) << 4)));
    }
    #pragma unroll
    for (int j = 0; j < 2; ++j)
      bfr[j] = *(const bf16x8*)(&kvs[(wc * 32 + j * 16 + lr) * LS + kk * 32 + lg * 8]);
    #pragma unroll
    for (int i = 0; i < 4; ++i)
      #pragma unroll
      for (int j = 0; j < 2; ++j)
        acc[i][j] = __builtin_amdgcn_mfma_f32_16x16x32_bf16(af[i], bfr[j], acc[i][j], 0, 0, 0);
  }
  #pragma unroll
  for (int i = 0; i < 4; ++i)
    #pragma unroll
    for (int j = 0; j < 2; ++j)
      #pragma unroll
      for (int r = 0; r < 4; ++r) {
        int rl = wr * 64 + i * 16 + lg * 4 + r;
        int d  = wc * 32 + j * 16 + lr;
        int t  = b * Ll + lt * 128 + rl;
        attn[(long)t * 512 + h * 64 + d] = f2b(acc[i][j][r] / den[rl]);
      }
}

// ---------------- LayerNorm, bf16 in -> bf16 out ----------------
__global__ __launch_bounds__(256) void k_ln_bb(const short* __restrict__ in, const float* __restrict__ sc,
                                               const float* __restrict__ bi, short* __restrict__ ob)
{
  int row = blockIdx.x * 4 + (threadIdx.x >> 6);
  int lane = threadIdx.x & 63;
  bf16x8 v = *((const bf16x8*)(in + (long)row * 512) + lane);
  float e[8];
  #pragma unroll
  for (int j = 0; j < 8; ++j) e[j] = b2f(v[j]);
  float s = 0.f, s2 = 0.f;
  #pragma unroll
  for (int j = 0; j < 8; ++j) { s += e[j]; s2 += e[j] * e[j]; }
  #pragma unroll
  for (int off = 32; off; off >>= 1) { s += __shfl_xor(s, off); s2 += __shfl_xor(s2, off); }
  float mu = s * (1.f / 512.f);
  float var = s2 * (1.f / 512.f) - mu * mu;
  float rstd = rsqrtf(var + 1e-6f);
  int c0 = lane * 8;
  bf16x8 o;
  #pragma unroll
  for (int j = 0; j < 8; ++j) o[j] = f2b((e[j] - mu) * rstd * sc[c0 + j] + bi[c0 + j]);
  *((bf16x8*)(ob + (long)row * 512) + lane) = o;
}

// ---------------- LayerNorm, bf16 in -> f32 out ----------------
__global__ __launch_bounds__(256) void k_ln_bf(const short* __restrict__ in, const float* __restrict__ sc,
                                               const float* __restrict__ bi, float* __restrict__ of)
{
  int row = blockIdx.x * 4 + (threadIdx.x >> 6);
  int lane = threadIdx.x & 63;
  bf16x8 v = *((const bf16x8*)(in + (long)row * 512) + lane);
  float e[8];
  #pragma unroll
  for (int j = 0; j < 8; ++j) e[j] = b2f(v[j]);
  float s = 0.f, s2 = 0.f;
  #pragma unroll
  for (int j = 0; j < 8; ++j) { s += e[j]; s2 += e[j] * e[j]; }
  #pragma unroll
  for (int off = 32; off; off >>= 1) { s += __shfl_xor(s, off); s2 += __shfl_xor(s2, off); }
  float mu = s * (1.f / 512.f);
  float var = s2 * (1.f / 512.f) - mu * mu;
  float rstd = rsqrtf(var + 1e-6f);
  int c0 = lane * 8;
  float o0[4], o1[4];
  #pragma unroll
  for (int j = 0; j < 4; ++j) {
    o0[j] = (e[j]     - mu) * rstd * sc[c0 + j]     + bi[c0 + j];
    o1[j] = (e[4 + j] - mu) * rstd * sc[c0 + 4 + j] + bi[c0 + 4 + j];
  }
  *(float4*)(of + (long)row * 512 + c0)     = (float4){o0[0], o0[1], o0[2], o0[3]};
  *(float4*)(of + (long)row * 512 + c0 + 4) = (float4){o1[0], o1[1], o1[2], o1[3]};
}

extern "C" void kernel_launch(void* const* d_in, const int* in_sizes, int n_in,
                              void* d_out, int out_size, void* d_ws, size_t ws_size,
                              hipStream_t stream)
{
  const float* x   = (const float*)d_in[0];
  const float* Wq  = (const float*)d_in[1];
  const float* bq  = (const float*)d_in[2];
  const float* Wk  = (const float*)d_in[3];
  const float* bk  = (const float*)d_in[4];
  const float* Wv  = (const float*)d_in[5];
  const float* bv  = (const float*)d_in[6];
  const float* Wo  = (const float*)d_in[7];
  const float* bo  = (const float*)d_in[8];
  const float* g1  = (const float*)d_in[9];
  const float* be1 = (const float*)d_in[10];
  const float* W1  = (const float*)d_in[11];
  const float* b1  = (const float*)d_in[12];
  const float* W2  = (const float*)d_in[13];
  const float* b2  = (const float*)d_in[14];
  const float* g2  = (const float*)d_in[15];
  const float* be2 = (const float*)d_in[16];
  float* out = (float*)d_out;

  const long MB = 1024L * 1024L;
  char* ws = (char*)d_ws;
  short* qp    = (short*)(ws + 0 * MB);
  short* kp    = (short*)(ws + 32 * MB);
  short* vb    = (short*)(ws + 64 * MB);
  short* attn  = (short*)(ws + 32 * MB);
  short* hb    = (short*)(ws + 0 * MB);
  short* hpreB = (short*)(ws + 64 * MB);
  short* ffa0  = (short*)(ws + 32 * MB);
  short* wqkvT = (short*)(ws + 96 * MB);
  short* woT   = (short*)(ws + 98 * MB);
  short* w1T   = (short*)(ws + 99 * MB);
  short* w2T   = (short*)(ws + 101 * MB);
  short* kvt   = (short*)(ws + 103 * MB);
  float* ksum  = (float*)(ws + 105 * MB);
  float* bqkv  = (float*)(ws + 105 * MB + 65536);

  short* xb   = (short*)d_out;
  float* kvp  = (float*)((char*)d_out + 32 * MB);
  float* ksp  = (float*)((char*)d_out + 48 * MB);
  short* ffa1 = (short*)d_out;

  dim3 tb(32, 8);
  k_cvt_x<<<8192, 256, 0, stream>>>(x, xb);
  k_tcvt4<<<dim3(16, 16, 4), tb, 0, stream>>>(Wq, Wk, Wv, Wo,
      wqkvT, wqkvT + 512 * 512, wqkvT + 1024 * 512, woT);
  k_tcvt<<<dim3(64, 16), tb, 0, stream>>>(W1, w1T, 512, 2048);
  k_tcvt<<<dim3(16, 64), tb, 0, stream>>>(W2, w2T, 2048, 512);
  k_pack_bias<<<6, 256, 0, stream>>>(bq, bk, bv, bqkv);

  k_gemm256<0, 512><<<768, 512, 0, stream>>>(xb, xb, wqkvT, 6, bqkv, nullptr, qp, kp, vb, nullptr);
  k_fkv_part<<<1024, 256, 0, stream>>>(kp, vb, kvp, ksp);
  k_fkv_reduce<<<4096, 256, 0, stream>>>(kvp, ksp, kvt, ksum);
  k_favor_num<<<2048, 256, 0, stream>>>(qp, kvt, ksum, attn);
  k_gemm256<1, 512><<<256, 512, 0, stream>>>(attn, attn, woT, 2, bo, xb, hpreB, nullptr, nullptr, nullptr);
  k_ln_bb<<<8192, 256, 0, stream>>>(hpreB, g1, be1, hb);
  k_gemm256<2, 512><<<1024, 512, 0, stream>>>(hb, hb, w1T, 8, b1, nullptr, ffa0, nullptr, nullptr, ffa1);
  k_gemm256<3, 2048><<<256, 512, 0, stream>>>(ffa0, ffa1, w2T, 2, b2, nullptr, hb, nullptr, nullptr, nullptr);
  k_ln_bf<<<8192, 256, 0, stream>>>(hb, g2, be2, out);
}

// Round 8
// 355.480 us; speedup vs baseline: 1.0342x; 1.0290x over previous
//
#include <hip/hip_runtime.h>

// Performer (FAVOR+) encoder block, bf16 MFMA pipeline. Round 8:
//  - 8-phase GEMM schedule + sched_barrier(0) pinning each phase's
//    ds_read+global_load_lds cluster BEFORE the barrier (rule-18 fix vs
//    compiler sinking reads past the barrier -> serialization)
//  - k_prep: cvt_x + all weight transposes + bias pack in ONE launch
// B=32 L=1024 HID=512 H=8 DH=64 FF=2048, N=32768 tokens.

#define DI __device__ __forceinline__
#define AS1 __attribute__((address_space(1)))
#define AS3 __attribute__((address_space(3)))
#define GLD16(g, l) __builtin_amdgcn_global_load_lds((const AS1 void*)(g), (AS3 void*)(l), 16, 0, 0)

typedef __attribute__((ext_vector_type(8))) short bf16x8;
typedef __attribute__((ext_vector_type(4))) float f32x4;

DI float b2f(short s){ unsigned int u = ((unsigned int)(unsigned short)s) << 16; float f; __builtin_memcpy(&f, &u, 4); return f; }
DI short f2b(float f){ unsigned int u; __builtin_memcpy(&u, &f, 4); u += 0x7fffu + ((u >> 16) & 1u); return (short)(u >> 16); }

constexpr int Ll = 1024;
constexpr int SPLIT = 16384;

// ---------------- unified prep: x->bf16, weight transposes, bias pack ----------------
// grid: [0,8192) cvt_x | [8192,+1024) Wq/Wk/Wv/Wo 32x32 tiles | +1024 W1 | +1024 W2 | +6 bias
__global__ __launch_bounds__(256) void k_prep(
    const float* __restrict__ x, short* __restrict__ xb,
    const float* __restrict__ Wq, const float* __restrict__ Wk,
    const float* __restrict__ Wv, const float* __restrict__ Wo,
    short* __restrict__ wqkvT, short* __restrict__ woT,
    const float* __restrict__ W1, short* __restrict__ w1T,
    const float* __restrict__ W2, short* __restrict__ w2T,
    const float* __restrict__ bq, const float* __restrict__ bk,
    const float* __restrict__ bv, float* __restrict__ bqkv)
{
  int bid = blockIdx.x;
  if (bid < 8192) {                       // x -> bf16, one bf16x8 per thread
    long i = (long)bid * 256 + threadIdx.x;
    const float4* p = (const float4*)x + i * 2;
    float4 a = p[0], b = p[1];
    bf16x8 o;
    o[0]=f2b(a.x); o[1]=f2b(a.y); o[2]=f2b(a.z); o[3]=f2b(a.w);
    o[4]=f2b(b.x); o[5]=f2b(b.y); o[6]=f2b(b.z); o[7]=f2b(b.w);
    *((bf16x8*)xb + i) = o;
    return;
  }
  bid -= 8192;
  if (bid < 3072) {                       // transpose+convert 32x32 tile
    __shared__ float t[32][33];
    const float* in; short* out; int R, C, bx, by;
    if (bid < 1024) {
      int z = bid >> 8, ti = bid & 255;
      bx = ti & 15; by = ti >> 4; R = 512; C = 512;
      in  = z == 0 ? Wq : z == 1 ? Wk : z == 2 ? Wv : Wo;
      out = z == 0 ? wqkvT : z == 1 ? wqkvT + 512 * 512 : z == 2 ? wqkvT + 1024 * 512 : woT;
    } else if (bid < 2048) {
      int ti = bid - 1024; bx = ti & 63; by = ti >> 6; R = 512; C = 2048; in = W1; out = w1T;
    } else {
      int ti = bid - 2048; bx = ti & 15; by = ti >> 4; R = 2048; C = 512; in = W2; out = w2T;
    }
    int c0 = bx * 32, r0 = by * 32;
    int xx = threadIdx.x & 31, yy = threadIdx.x >> 5;   // (32,8)
    #pragma unroll
    for (int j = 0; j < 4; ++j) t[yy + 8*j][xx] = in[(long)(r0 + yy + 8*j) * C + c0 + xx];
    __syncthreads();
    #pragma unroll
    for (int j = 0; j < 4; ++j) out[(long)(c0 + yy + 8*j) * R + r0 + xx] = f2b(t[xx][yy + 8*j]);
    return;
  }
  bid -= 3072;                            // bias pack (6 blocks)
  int i = bid * 256 + threadIdx.x;
  if (i < 512) bqkv[i] = bq[i];
  else if (i < 1024) bqkv[i] = bk[i - 512];
  else if (i < 1536) bqkv[i] = bv[i - 1024];
}

// ---------------- 256x256 bf16 MFMA GEMM, 8 waves, 8-phase schedule ----------------
// LDS (128 KiB): A[buf][half][128][64] | B[buf][half][128][64]; 16B slot s of row r
// holds global chunk s^(r&7). Wave (wm,wn): out 128x64. Stage map per iteration
// (K-tiles t0 buf0 / t1 buf1):
//  p1:A1lo<-t1 p2:A1hi<-t1 p3:B0lo<-t0+2 p4:B0hi<-t0+2 +vmcnt(4)
//  p5:A0lo<-t0+2 p6:A0hi<-t0+2 p7:B1lo<-t1+2 p8:B1hi<-t1+2 +vmcnt(4)
// sched_barrier(0) pins each phase's read+stage cluster before its barrier.
// vmcnt ledger (per thread GLD16): steady-state 12 in flight, gate leaves 4.
// EPI: 0=QKV(phi) 1=attn-out(+bo+xb) 2=FFN1(relu, row-split) 3=FFN2(+b2+oQ in-place)
template<int EPI, int KD>
__global__ __launch_bounds__(512, 2) void k_gemm256(
    const short* __restrict__ A0, const short* __restrict__ A1,
    const short* __restrict__ BT, int NT,
    const float* __restrict__ bias, const short* __restrict__ residX,
    short* __restrict__ oQ, short* __restrict__ oK, short* __restrict__ oV,
    short* __restrict__ o1)
{
  __shared__ short lds[65536];
  const int tid = threadIdx.x;
  const int w = tid >> 6, lane = tid & 63;
  const int wm = w >> 2, wn = w & 3;
  const int lg = lane >> 4, lr = lane & 15;
  const int lrow = lane >> 3, lslot = (lane & 7) ^ lrow;

  const int per = gridDim.x >> 3;
  const int wg = (blockIdx.x & 7) * per + (blockIdx.x >> 3);
  const long m0 = (long)(wg / NT) * 256, n0 = (long)(wg % NT) * 256;

  const short* Ause = A0;
  long mbase = m0;
  if (A1 != A0 && m0 >= SPLIT) { Ause = A1; mbase = m0 - SPLIT; }

  f32x4 acc[8][4];
  #pragma unroll
  for (int i = 0; i < 8; ++i)
    #pragma unroll
    for (int j = 0; j < 4; ++j) acc[i][j] = 0.f;

  const char* Abase = (const char*)lds + wm * 16384;
  const char* Bbase = (const char*)lds + 65536 + (wn >> 1) * 16384;

#define STAGE_A(buf, half, t) do {                                              \
    int k0_ = (t) * 64;                                                         \
    _Pragma("unroll")                                                           \
    for (int q_ = 0; q_ < 2; ++q_) {                                            \
      int rs_ = w * 16 + q_ * 8;                                                \
      GLD16(Ause + (mbase + (half) * 128 + rs_ + lrow) * KD + k0_ + lslot * 8,  \
            (char*)lds + ((buf) * 16384 + (half) * 8192 + rs_ * 64) * 2);       \
    } } while (0)
#define STAGE_B(buf, half, t) do {                                              \
    int k0_ = (t) * 64;                                                         \
    _Pragma("unroll")                                                           \
    for (int q_ = 0; q_ < 2; ++q_) {                                            \
      int rs_ = w * 16 + q_ * 8;                                                \
      GLD16(BT + (n0 + (half) * 128 + rs_ + lrow) * KD + k0_ + lslot * 8,       \
            (char*)lds + (32768 + (buf) * 16384 + (half) * 8192 + rs_ * 64) * 2); \
    } } while (0)
#define READ_A(buf, qr) do {                                                    \
    _Pragma("unroll")                                                           \
    for (int i_ = 0; i_ < 4; ++i_)                                              \
      _Pragma("unroll")                                                         \
      for (int kk_ = 0; kk_ < 2; ++kk_) {                                       \
        int ra_ = (qr) * 64 + i_ * 16 + lr;                                     \
        fA[i_][kk_] = *(const bf16x8*)(Abase + (buf) * 32768 + ra_ * 128 +      \
                       ((kk_ * 64 + lg * 16) ^ ((ra_ & 7) << 4)));              \
      } } while (0)
#define READ_B(FB, buf, qc) do {                                                \
    _Pragma("unroll")                                                           \
    for (int j_ = 0; j_ < 2; ++j_)                                              \
      _Pragma("unroll")                                                         \
      for (int kk_ = 0; kk_ < 2; ++kk_) {                                       \
        int rb_ = (wn & 1) * 64 + (qc) * 32 + j_ * 16 + lr;                     \
        FB[j_][kk_] = *(const bf16x8*)(Bbase + (buf) * 32768 + rb_ * 128 +      \
                       ((kk_ * 64 + lg * 16) ^ ((rb_ & 7) << 4)));              \
      } } while (0)
#define MFMA_Q(qr, qc, FB) do {                                                 \
    __builtin_amdgcn_s_setprio(1);                                              \
    _Pragma("unroll")                                                           \
    for (int i_ = 0; i_ < 4; ++i_)                                              \
      _Pragma("unroll")                                                         \
      for (int j_ = 0; j_ < 2; ++j_)                                            \
        _Pragma("unroll")                                                       \
        for (int kk_ = 0; kk_ < 2; ++kk_)                                       \
          acc[(qr)*4+i_][(qc)*2+j_] = __builtin_amdgcn_mfma_f32_16x16x32_bf16(  \
              fA[i_][kk_], FB[j_][kk_], acc[(qr)*4+i_][(qc)*2+j_], 0, 0, 0);    \
    __builtin_amdgcn_s_setprio(0);                                              \
  } while (0)
#define SPIN __builtin_amdgcn_sched_barrier(0)
#define BARR __builtin_amdgcn_s_barrier()
#define GATEC asm volatile("s_waitcnt vmcnt(4)" ::: "memory")
#define GATE0 asm volatile("s_waitcnt vmcnt(0)" ::: "memory")

  constexpr int NKT = KD / 64;
  bf16x8 fA[4][2], fB0[2][2], fB1[2][2];

  // prologue: K0 fully, K1 B-halves (A1 staged in p1/p2 of iter 0)
  STAGE_A(0, 0, 0); STAGE_A(0, 1, 0); STAGE_B(0, 0, 0); STAGE_B(0, 1, 0);
  STAGE_B(1, 0, 1); STAGE_B(1, 1, 1);
  GATEC; BARR;                       // K0's 8 landed; B1's 4 in flight

  for (int it = 0; it < NKT / 2; ++it) {
    const int t0 = 2 * it, t1 = 2 * it + 1;
    const bool s0 = (t0 + 2 < NKT), s1 = (t1 + 2 < NKT);
    // p1
    READ_A(0, 0); READ_B(fB0, 0, 0); STAGE_A(1, 0, t1); SPIN;
    BARR; MFMA_Q(0, 0, fB0); BARR;
    // p2
    READ_B(fB1, 0, 1); STAGE_A(1, 1, t1); SPIN;
    BARR; MFMA_Q(0, 1, fB1); BARR;
    // p3
    READ_A(0, 1); if (s0) STAGE_B(0, 0, t0 + 2); SPIN;
    BARR; MFMA_Q(1, 0, fB0); BARR;
    // p4
    if (s0) { STAGE_B(0, 1, t0 + 2); SPIN; GATEC; } else { SPIN; GATE0; }
    BARR; MFMA_Q(1, 1, fB1); BARR;
    // p5
    READ_A(1, 0); READ_B(fB0, 1, 0); if (s0) STAGE_A(0, 0, t0 + 2); SPIN;
    BARR; MFMA_Q(0, 0, fB0); BARR;
    // p6
    READ_B(fB1, 1, 1); if (s0) STAGE_A(0, 1, t0 + 2); SPIN;
    BARR; MFMA_Q(0, 1, fB1); BARR;
    // p7
    READ_A(1, 1); if (s1) STAGE_B(1, 0, t1 + 2); SPIN;
    BARR; MFMA_Q(1, 0, fB0); BARR;
    // p8
    if (s1) { STAGE_B(1, 1, t1 + 2); SPIN; GATEC; } else { SPIN; GATE0; }
    BARR; MFMA_Q(1, 1, fB1); BARR;
  }

#undef STAGE_A
#undef STAGE_B
#undef READ_A
#undef READ_B
#undef MFMA_Q
#undef SPIN
#undef BARR
#undef GATEC
#undef GATE0

  #pragma unroll
  for (int fr = 0; fr < 8; ++fr)
    #pragma unroll
    for (int fc = 0; fc < 4; ++fc)
      #pragma unroll
      for (int r = 0; r < 4; ++r) {
        int grow = (int)m0 + wm * 128 + fr * 16 + lg * 4 + r;  // C/D: row=(lane>>4)*4+reg
        int gcol = (int)n0 + wn * 64 + fc * 16 + lr;           //      col=lane&15
        float v = acc[fr][fc][r];
        if constexpr (EPI == 0) {
          v += bias[gcol];
          int which = gcol >> 9, hd = gcol & 511, h = hd >> 6, d = hd & 63;
          int b = grow >> 10, l = grow & 1023;
          long o = ((long)(b * 8 + h) * 1024 + l) * 64 + d;
          if (which == 2) oV[o] = f2b(v);
          else { float p = fmaxf(v, 0.f) + 1e-3f; if (which) oK[o] = f2b(p); else oQ[o] = f2b(p); }
        } else if constexpr (EPI == 1) {
          v += bias[gcol] + b2f(residX[(long)grow * 512 + gcol]);
          oQ[(long)grow * 512 + gcol] = f2b(v);
        } else if constexpr (EPI == 2) {
          v = fmaxf(v + bias[gcol], 0.f);
          if (grow < SPLIT) oQ[(long)grow * 2048 + gcol] = f2b(v);
          else              o1[(long)(grow - SPLIT) * 2048 + gcol] = f2b(v);
        } else {
          long idx = (long)grow * 512 + gcol;
          v += bias[gcol] + b2f(oQ[idx]);
          oQ[idx] = f2b(v);
        }
      }
}

// ---------------- FAVOR kv partials ----------------
__global__ __launch_bounds__(256) void k_fkv_part(const short* __restrict__ kp, const short* __restrict__ vb,
                                                  float* __restrict__ kvp, float* __restrict__ ksp)
{
  constexpr int LS = 72;
  __shared__ short kps[64 * LS];
  __shared__ short vps[64 * LS];
  int bh = blockIdx.x & 255, c = blockIdx.x >> 8;
  const short* kpp = kp + (long)bh * Ll * 64;
  const short* vpp = vb + (long)bh * Ll * 64;
  int tid = threadIdx.x;
  int mb = (tid & 15) * 4, db = (tid >> 4) * 4;
  float acc[4][4];
  float ks[4] = {0.f, 0.f, 0.f, 0.f};
  #pragma unroll
  for (int i = 0; i < 4; ++i)
    #pragma unroll
    for (int j = 0; j < 4; ++j) acc[i][j] = 0.f;

  for (int l0 = c * 256; l0 < c * 256 + 256; l0 += 64) {
    __syncthreads();
    #pragma unroll
    for (int s = 0; s < 2; ++s) {
      int idx = tid + s * 256;
      int row = idx >> 3, c8 = idx & 7;
      *(bf16x8*)(&kps[row * LS + c8 * 8]) = *(const bf16x8*)(kpp + (long)(l0 + row) * 64 + c8 * 8);
      *(bf16x8*)(&vps[row * LS + c8 * 8]) = *(const bf16x8*)(vpp + (long)(l0 + row) * 64 + c8 * 8);
    }
    __syncthreads();
    #pragma unroll 4
    for (int l = 0; l < 64; ++l) {
      short4 ka = *(const short4*)(&kps[l * LS + mb]);
      short4 va = *(const short4*)(&vps[l * LS + db]);
      float kf[4] = {b2f(ka.x), b2f(ka.y), b2f(ka.z), b2f(ka.w)};
      float vf[4] = {b2f(va.x), b2f(va.y), b2f(va.z), b2f(va.w)};
      if (tid < 16) { ks[0] += kf[0]; ks[1] += kf[1]; ks[2] += kf[2]; ks[3] += kf[3]; }
      #pragma unroll
      for (int i = 0; i < 4; ++i)
        #pragma unroll
        for (int j = 0; j < 4; ++j) acc[i][j] += kf[i] * vf[j];
    }
  }
  float* kout = kvp + (long)c * 1048576 + (long)bh * 4096;
  #pragma unroll
  for (int i = 0; i < 4; ++i)
    #pragma unroll
    for (int j = 0; j < 4; ++j)
      kout[(db + j) * 64 + mb + i] = acc[i][j];
  if (tid < 16) {
    #pragma unroll
    for (int i = 0; i < 4; ++i) ksp[(long)c * 16384 + bh * 64 + mb + i] = ks[i];
  }
}

__global__ __launch_bounds__(256) void k_fkv_reduce(const float* __restrict__ kvp, const float* __restrict__ ksp,
                                                    short* __restrict__ kvt, float* __restrict__ ksum)
{
  int g = blockIdx.x * 256 + threadIdx.x;
  float s = kvp[g] + kvp[g + 1048576] + kvp[g + 2 * 1048576] + kvp[g + 3 * 1048576];
  kvt[g] = f2b(s);
  if (g < 16384)
    ksum[g] = ksp[g] + ksp[g + 16384] + ksp[g + 2 * 16384] + ksp[g + 3 * 16384];
}

// ---------------- FAVOR: attn = (qp @ kv)/den ----------------
__global__ __launch_bounds__(256) void k_favor_num(const short* __restrict__ qp, const short* __restrict__ kvt,
                                                   const float* __restrict__ ksum, short* __restrict__ attn)
{
  constexpr int LS = 72;
  __shared__ short Qs[128 * 64];
  __shared__ short kvs[64 * LS];
  __shared__ float part[256];
  __shared__ float den[128];
  int bh = blockIdx.x >> 3, lt = blockIdx.x & 7;
  int b = bh >> 3, h = bh & 7;
  const short* qpp = qp + ((long)bh * Ll + lt * 128) * 64;
  int tid = threadIdx.x;
  int wave = tid >> 6, lane = tid & 63;
  int lrow = lane >> 3, lslot = (lane & 7) ^ lrow;

  #pragma unroll
  for (int s = 0; s < 4; ++s) {
    int rs = (s * 4 + wave) * 8;
    GLD16(qpp + (long)(rs + lrow) * 64 + lslot * 8, &Qs[rs * 64]);
  }
  #pragma unroll
  for (int s = 0; s < 2; ++s) {
    int idx = tid + s * 256;
    int row = idx >> 3, c8 = idx & 7;
    *(bf16x8*)(&kvs[row * LS + c8 * 8]) = *(const bf16x8*)(kvt + (long)bh * 4096 + row * 64 + c8 * 8);
  }
  __syncthreads();
  {
    int r = tid >> 1, half = tid & 1;
    const float* kss = ksum + bh * 64 + half * 32;
    float s = 0.f;
    #pragma unroll
    for (int c = 0; c < 4; ++c) {
      int cc = half * 4 + c;
      bf16x8 v = *(const bf16x8*)((const char*)Qs + r * 128 + ((cc * 16) ^ ((r & 7) << 4)));
      #pragma unroll
      for (int j = 0; j < 8; ++j) s += b2f(v[j]) * kss[c * 8 + j];
    }
    part[tid] = s;
  }
  __syncthreads();
  if (tid < 128) den[tid] = part[2 * tid] + part[2 * tid + 1];
  __syncthreads();

  int wr = wave >> 1, wc = wave & 1;
  int lg = lane >> 4, lr = lane & 15;
  f32x4 acc[4][2];
  #pragma unroll
  for (int i = 0; i < 4; ++i) { acc[i][0] = 0.f; acc[i][1] = 0.f; }
  #pragma unroll
  for (int kk = 0; kk < 2; ++kk) {
    bf16x8 af[4], bfr[2];
    #pragma unroll
    for (int i = 0; i < 4; ++i) {
      int ra = wr * 64 + i * 16 + lr;
      af[i] = *(const bf16x8*)((const char*)Qs + ra * 128 + ((kk * 64 + lg * 16) ^ ((ra & 7) << 4)));
    }
    #pragma unroll
    for (int j = 0; j < 2; ++j)
      bfr[j] = *(const bf16x8*)(&kvs[(wc * 32 + j * 16 + lr) * LS + kk * 32 + lg * 8]);
    #pragma unroll
    for (int i = 0; i < 4; ++i)
      #pragma unroll
      for (int j = 0; j < 2; ++j)
        acc[i][j] = __builtin_amdgcn_mfma_f32_16x16x32_bf16(af[i], bfr[j], acc[i][j], 0, 0, 0);
  }
  #pragma unroll
  for (int i = 0; i < 4; ++i)
    #pragma unroll
    for (int j = 0; j < 2; ++j)
      #pragma unroll
      for (int r = 0; r < 4; ++r) {
        int rl = wr * 64 + i * 16 + lg * 4 + r;
        int d  = wc * 32 + j * 16 + lr;
        int t  = b * Ll + lt * 128 + rl;
        attn[(long)t * 512 + h * 64 + d] = f2b(acc[i][j][r] / den[rl]);
      }
}

// ---------------- LayerNorm, bf16 in -> bf16 out ----------------
__global__ __launch_bounds__(256) void k_ln_bb(const short* __restrict__ in, const float* __restrict__ sc,
                                               const float* __restrict__ bi, short* __restrict__ ob)
{
  int row = blockIdx.x * 4 + (threadIdx.x >> 6);
  int lane = threadIdx.x & 63;
  bf16x8 v = *((const bf16x8*)(in + (long)row * 512) + lane);
  float e[8];
  #pragma unroll
  for (int j = 0; j < 8; ++j) e[j] = b2f(v[j]);
  float s = 0.f, s2 = 0.f;
  #pragma unroll
  for (int j = 0; j < 8; ++j) { s += e[j]; s2 += e[j] * e[j]; }
  #pragma unroll
  for (int off = 32; off; off >>= 1) { s += __shfl_xor(s, off); s2 += __shfl_xor(s2, off); }
  float mu = s * (1.f / 512.f);
  float var = s2 * (1.f / 512.f) - mu * mu;
  float rstd = rsqrtf(var + 1e-6f);
  int c0 = lane * 8;
  bf16x8 o;
  #pragma unroll
  for (int j = 0; j < 8; ++j) o[j] = f2b((e[j] - mu) * rstd * sc[c0 + j] + bi[c0 + j]);
  *((bf16x8*)(ob + (long)row * 512) + lane) = o;
}

// ---------------- LayerNorm, bf16 in -> f32 out ----------------
__global__ __launch_bounds__(256) void k_ln_bf(const short* __restrict__ in, const float* __restrict__ sc,
                                               const float* __restrict__ bi, float* __restrict__ of)
{
  int row = blockIdx.x * 4 + (threadIdx.x >> 6);
  int lane = threadIdx.x & 63;
  bf16x8 v = *((const bf16x8*)(in + (long)row * 512) + lane);
  float e[8];
  #pragma unroll
  for (int j = 0; j < 8; ++j) e[j] = b2f(v[j]);
  float s = 0.f, s2 = 0.f;
  #pragma unroll
  for (int j = 0; j < 8; ++j) { s += e[j]; s2 += e[j] * e[j]; }
  #pragma unroll
  for (int off = 32; off; off >>= 1) { s += __shfl_xor(s, off); s2 += __shfl_xor(s2, off); }
  float mu = s * (1.f / 512.f);
  float var = s2 * (1.f / 512.f) - mu * mu;
  float rstd = rsqrtf(var + 1e-6f);
  int c0 = lane * 8;
  float o0[4], o1[4];
  #pragma unroll
  for (int j = 0; j < 4; ++j) {
    o0[j] = (e[j]     - mu) * rstd * sc[c0 + j]     + bi[c0 + j];
    o1[j] = (e[4 + j] - mu) * rstd * sc[c0 + 4 + j] + bi[c0 + 4 + j];
  }
  *(float4*)(of + (long)row * 512 + c0)     = (float4){o0[0], o0[1], o0[2], o0[3]};
  *(float4*)(of + (long)row * 512 + c0 + 4) = (float4){o1[0], o1[1], o1[2], o1[3]};
}

extern "C" void kernel_launch(void* const* d_in, const int* in_sizes, int n_in,
                              void* d_out, int out_size, void* d_ws, size_t ws_size,
                              hipStream_t stream)
{
  const float* x   = (const float*)d_in[0];
  const float* Wq  = (const float*)d_in[1];
  const float* bq  = (const float*)d_in[2];
  const float* Wk  = (const float*)d_in[3];
  const float* bk  = (const float*)d_in[4];
  const float* Wv  = (const float*)d_in[5];
  const float* bv  = (const float*)d_in[6];
  const float* Wo  = (const float*)d_in[7];
  const float* bo  = (const float*)d_in[8];
  const float* g1  = (const float*)d_in[9];
  const float* be1 = (const float*)d_in[10];
  const float* W1  = (const float*)d_in[11];
  const float* b1  = (const float*)d_in[12];
  const float* W2  = (const float*)d_in[13];
  const float* b2  = (const float*)d_in[14];
  const float* g2  = (const float*)d_in[15];
  const float* be2 = (const float*)d_in[16];
  float* out = (float*)d_out;

  const long MB = 1024L * 1024L;
  char* ws = (char*)d_ws;
  short* qp    = (short*)(ws + 0 * MB);
  short* kp    = (short*)(ws + 32 * MB);
  short* vb    = (short*)(ws + 64 * MB);
  short* attn  = (short*)(ws + 32 * MB);
  short* hb    = (short*)(ws + 0 * MB);
  short* hpreB = (short*)(ws + 64 * MB);
  short* ffa0  = (short*)(ws + 32 * MB);
  short* wqkvT = (short*)(ws + 96 * MB);
  short* woT   = (short*)(ws + 98 * MB);
  short* w1T   = (short*)(ws + 99 * MB);
  short* w2T   = (short*)(ws + 101 * MB);
  short* kvt   = (short*)(ws + 103 * MB);
  float* ksum  = (float*)(ws + 105 * MB);
  float* bqkv  = (float*)(ws + 105 * MB + 65536);

  short* xb   = (short*)d_out;
  float* kvp  = (float*)((char*)d_out + 32 * MB);
  float* ksp  = (float*)((char*)d_out + 48 * MB);
  short* ffa1 = (short*)d_out;

  k_prep<<<11270, 256, 0, stream>>>(x, xb, Wq, Wk, Wv, Wo, wqkvT, woT,
                                    W1, w1T, W2, w2T, bq, bk, bv, bqkv);

  k_gemm256<0, 512><<<768, 512, 0, stream>>>(xb, xb, wqkvT, 6, bqkv, nullptr, qp, kp, vb, nullptr);
  k_fkv_part<<<1024, 256, 0, stream>>>(kp, vb, kvp, ksp);
  k_fkv_reduce<<<4096, 256, 0, stream>>>(kvp, ksp, kvt, ksum);
  k_favor_num<<<2048, 256, 0, stream>>>(qp, kvt, ksum, attn);
  k_gemm256<1, 512><<<256, 512, 0, stream>>>(attn, attn, woT, 2, bo, xb, hpreB, nullptr, nullptr, nullptr);
  k_ln_bb<<<8192, 256, 0, stream>>>(hpreB, g1, be1, hb);
  k_gemm256<2, 512><<<1024, 512, 0, stream>>>(hb, hb, w1T, 8, b1, nullptr, ffa0, nullptr, nullptr, ffa1);
  k_gemm256<3, 2048><<<256, 512, 0, stream>>>(ffa0, ffa1, w2T, 2, b2, nullptr, hb, nullptr, nullptr, nullptr);
  k_ln_bf<<<8192, 256, 0, stream>>>(hb, g2, be2, out);
}